// Round 1
// baseline (1437.029 us; speedup 1.0000x reference)
//
#include <hip/hip_runtime.h>
#include <cstddef>
#include <cstdint>
#include <math.h>

// Problem constants (match reference setup_inputs)
constexpr int Bc = 4;
constexpr int Tc = 2048;
constexpr int Dc = 1024;
constexpr int DMc = 512;
constexpr int Hc = 8;
constexpr int DKc = 128;
constexpr int Nc = Bc * Tc;       // 8192 rows
constexpr int TOPKc = 16;

// ---------------------------------------------------------------------------
// K1: LayerNorm.  One block (256 thr) per row; float4 loads; block reduce.
// ---------------------------------------------------------------------------
__global__ __launch_bounds__(256) void ln_kernel(const float* __restrict__ x,
                                                 const float* __restrict__ g,
                                                 const float* __restrict__ b,
                                                 float* __restrict__ h) {
    int row = blockIdx.x;
    const float4* xr = (const float4*)(x + (size_t)row * Dc);
    float4 v = xr[threadIdx.x];
    float s  = v.x + v.y + v.z + v.w;
    float ss = v.x * v.x + v.y * v.y + v.z * v.z + v.w * v.w;
    #pragma unroll
    for (int off = 1; off < 64; off <<= 1) {
        s  += __shfl_xor(s,  off, 64);
        ss += __shfl_xor(ss, off, 64);
    }
    __shared__ float rs[4], rss[4];
    int wv = threadIdx.x >> 6, ln = threadIdx.x & 63;
    if (ln == 0) { rs[wv] = s; rss[wv] = ss; }
    __syncthreads();
    s  = rs[0] + rs[1] + rs[2] + rs[3];
    ss = rss[0] + rss[1] + rss[2] + rss[3];
    float mu  = s * (1.0f / Dc);
    float var = ss * (1.0f / Dc) - mu * mu;
    float rstd = rsqrtf(var + 1e-5f);
    float4 gg = ((const float4*)g)[threadIdx.x];
    float4 bb = ((const float4*)b)[threadIdx.x];
    float4 o;
    o.x = (v.x - mu) * rstd * gg.x + bb.x;
    o.y = (v.y - mu) * rstd * gg.y + bb.y;
    o.z = (v.z - mu) * rstd * gg.z + bb.z;
    o.w = (v.w - mu) * rstd * gg.w + bb.w;
    ((float4*)(h + (size_t)row * Dc))[threadIdx.x] = o;
}

// ---------------------------------------------------------------------------
// K2a: column-sum of h_in over T (first 512 dims only) -> qsum via atomics.
// grid (B, 64) blocks, each handles 32 rows.
// ---------------------------------------------------------------------------
__global__ __launch_bounds__(256) void qsum_kernel(const float* __restrict__ h,
                                                   float* __restrict__ qsum) {
    int b = blockIdx.x;
    int chunk = blockIdx.y;
    int d0 = threadIdx.x, d1 = threadIdx.x + 256;
    const float* base = h + ((size_t)b * Tc + (size_t)chunk * 32) * Dc;
    float a0 = 0.f, a1 = 0.f;
    #pragma unroll 4
    for (int r = 0; r < 32; ++r) {
        a0 += base[(size_t)r * Dc + d0];
        a1 += base[(size_t)r * Dc + d1];
    }
    atomicAdd(&qsum[b * DMc + d0], a0);
    atomicAdd(&qsum[b * DMc + d1], a1);
}

// K2b: normalize q summary: qn = (qsum/T) / max(||qsum/T||, 1e-12)
__global__ __launch_bounds__(256) void qnorm_kernel(const float* __restrict__ qsum,
                                                    float* __restrict__ qn) {
    int b = blockIdx.x;
    float v0 = qsum[b * DMc + threadIdx.x] * (1.0f / Tc);
    float v1 = qsum[b * DMc + threadIdx.x + 256] * (1.0f / Tc);
    float ss = v0 * v0 + v1 * v1;
    #pragma unroll
    for (int off = 1; off < 64; off <<= 1) ss += __shfl_xor(ss, off, 64);
    __shared__ float red[4];
    int wv = threadIdx.x >> 6, ln = threadIdx.x & 63;
    if (ln == 0) red[wv] = ss;
    __syncthreads();
    ss = red[0] + red[1] + red[2] + red[3];
    float inv = 1.0f / fmaxf(sqrtf(ss), 1e-12f);
    qn[b * DMc + threadIdx.x] = v0 * inv;
    qn[b * DMc + threadIdx.x + 256] = v1 * inv;
}

__device__ inline float dot4(float4 a, float4 b) {
    return a.x * b.x + a.y * b.y + a.z * b.z + a.w * b.w;
}

// ---------------------------------------------------------------------------
// K3: sim[b][r] = dot(qn[b], keys[r]) / max(||keys[r]||, 1e-12)
// One wave per row, grid-stride. 205 MB read -> HBM-bound.
// ---------------------------------------------------------------------------
__global__ __launch_bounds__(256) void sim_kernel(const float* __restrict__ keys,
                                                  const float* __restrict__ qn,
                                                  float* __restrict__ sim, int M) {
    int lane = threadIdx.x & 63;
    int wave = (blockIdx.x * 256 + threadIdx.x) >> 6;
    int nw = (gridDim.x * 256) >> 6;
    // preload qn fragments for this lane's element positions (8 floats x 4 b)
    const float4* qf = (const float4*)qn;  // 128 float4 per b
    float4 q[4][2];
    #pragma unroll
    for (int b = 0; b < 4; ++b) {
        q[b][0] = qf[b * 128 + lane];
        q[b][1] = qf[b * 128 + 64 + lane];
    }
    for (int r = wave; r < M; r += nw) {
        const float4* kr = (const float4*)(keys + (size_t)r * DMc);
        float4 k0 = kr[lane], k1 = kr[lane + 64];
        float nn = dot4(k0, k0) + dot4(k1, k1);
        float d0 = dot4(k0, q[0][0]) + dot4(k1, q[0][1]);
        float d1 = dot4(k0, q[1][0]) + dot4(k1, q[1][1]);
        float d2 = dot4(k0, q[2][0]) + dot4(k1, q[2][1]);
        float d3 = dot4(k0, q[3][0]) + dot4(k1, q[3][1]);
        #pragma unroll
        for (int off = 1; off < 64; off <<= 1) {
            nn += __shfl_xor(nn, off, 64);
            d0 += __shfl_xor(d0, off, 64);
            d1 += __shfl_xor(d1, off, 64);
            d2 += __shfl_xor(d2, off, 64);
            d3 += __shfl_xor(d3, off, 64);
        }
        if (lane == 0) {
            float inv = 1.0f / fmaxf(sqrtf(nn), 1e-12f);
            sim[(size_t)0 * M + r] = d0 * inv;
            sim[(size_t)1 * M + r] = d1 * inv;
            sim[(size_t)2 * M + r] = d2 * inv;
            sim[(size_t)3 * M + r] = d3 * inv;
        }
    }
}

// ---------------------------------------------------------------------------
// K4: top-16 per b. One block per b. Per-thread local top-16 then LDS merge.
// Only the SET of indices matters (attention is permutation-invariant in k).
// ---------------------------------------------------------------------------
__global__ __launch_bounds__(256) void topk_kernel(const float* __restrict__ sim,
                                                   int* __restrict__ top_idx, int M) {
    int b = blockIdx.x;
    float lv[TOPKc];
    int li[TOPKc];
    #pragma unroll
    for (int i = 0; i < TOPKc; ++i) { lv[i] = -3e38f; li[i] = -1; }
    float vmin = -3e38f;
    for (int i = threadIdx.x; i < M; i += 256) {
        float v = sim[(size_t)b * M + i];
        if (v > vmin) {
            int p = 0;
            while (p < TOPKc - 1 && v > lv[p + 1]) { lv[p] = lv[p + 1]; li[p] = li[p + 1]; ++p; }
            lv[p] = v; li[p] = i;
            vmin = lv[0];
        }
    }
    __shared__ float sv[256 * 17];
    __shared__ int   si[256 * 17];
    #pragma unroll
    for (int i = 0; i < TOPKc; ++i) {
        sv[threadIdx.x * 17 + i] = lv[i];
        si[threadIdx.x * 17 + i] = li[i];
    }
    __shared__ float rv[256];
    __shared__ int   ri[256];
    __syncthreads();
    for (int sel = 0; sel < TOPKc; ++sel) {
        float bv = -3e38f; int bslot = -1;
        #pragma unroll
        for (int i = 0; i < TOPKc; ++i) {
            float v = sv[threadIdx.x * 17 + i];
            if (v > bv) { bv = v; bslot = threadIdx.x * 17 + i; }
        }
        rv[threadIdx.x] = bv; ri[threadIdx.x] = bslot;
        __syncthreads();
        for (int s = 128; s > 0; s >>= 1) {
            if (threadIdx.x < s) {
                if (rv[threadIdx.x + s] > rv[threadIdx.x]) {
                    rv[threadIdx.x] = rv[threadIdx.x + s];
                    ri[threadIdx.x] = ri[threadIdx.x + s];
                }
            }
            __syncthreads();
        }
        if (threadIdx.x == 0) {
            int slot = ri[0];
            top_idx[b * TOPKc + sel] = si[slot];
            sv[slot] = -3e38f;
        }
        __syncthreads();
    }
}

// ---------------------------------------------------------------------------
// K5: gather + K/V projection.  128 blocks: (kv, b, kk).  K[b,kk,:] =
// mem_row @ W.T + bias   (W is (1024,512) row-major; out 1024 wide)
// ---------------------------------------------------------------------------
__global__ __launch_bounds__(256) void kv_kernel(const float* __restrict__ memk,
                                                 const float* __restrict__ memv,
                                                 const int* __restrict__ top_idx,
                                                 const float* __restrict__ kW,
                                                 const float* __restrict__ kb,
                                                 const float* __restrict__ vW,
                                                 const float* __restrict__ vb,
                                                 float* __restrict__ Kbuf,
                                                 float* __restrict__ Vbuf) {
    int id = blockIdx.x;
    int kv = id >> 6;
    int b = (id >> 4) & 3;
    int kk = id & 15;
    int ridx = top_idx[b * TOPKc + kk];
    const float* src = (kv ? memv : memk) + (size_t)ridx * DMc;
    const float* W = kv ? vW : kW;
    const float* bias = kv ? vb : kb;
    float* dst = (kv ? Vbuf : Kbuf) + (size_t)(b * TOPKc + kk) * Dc;
    __shared__ float srow[DMc];
    if (threadIdx.x < 128) ((float4*)srow)[threadIdx.x] = ((const float4*)src)[threadIdx.x];
    __syncthreads();
    #pragma unroll
    for (int jj = 0; jj < 4; ++jj) {
        int j = threadIdx.x + jj * 256;
        const float4* wr = (const float4*)(W + (size_t)j * DMc);
        float acc = 0.f;
        #pragma unroll 4
        for (int c = 0; c < DMc / 4; ++c) {
            float4 w = wr[c];
            float4 s = ((const float4*)srow)[c];
            acc += w.x * s.x + w.y * s.y + w.z * s.z + w.w * s.w;
        }
        dst[j] = acc + bias[j];
    }
}

// ---------------------------------------------------------------------------
// K6: fp32 tiled GEMM  C(N x NOUT) = A(N x 1024) @ W(NOUT x 1024)^T + bias
// 128x128 tile, BK=16, 256 threads, 8x8 acc/thread.
// MODE 0: plain (Q proj)   MODE 1: gelu (G1)   MODE 2: out = x + gate*(.)
// ---------------------------------------------------------------------------
__device__ inline float gelu_exact(float v) {
    return 0.5f * v * (1.0f + erff(v * 0.70710678118654752f));
}

template <int MODE, int NOUT>
__global__ __launch_bounds__(256) void gemm_kernel(const float* __restrict__ A,
                                                   const float* __restrict__ W,
                                                   const float* __restrict__ bias,
                                                   float* __restrict__ C,
                                                   const float* __restrict__ xres,
                                                   const float* __restrict__ gate) {
    __shared__ float As[16][132];
    __shared__ float Bs[16][132];
    int i0 = blockIdx.x * 128;
    int j0 = blockIdx.y * 128;
    int tid = threadIdx.x;
    int lane = tid & 63, wave = tid >> 6;
    int ty = ((wave >> 1) << 3) + (lane >> 3);   // 0..15
    int tx = ((wave & 1) << 3) + (lane & 7);     // 0..15
    int r = ty * 8, c = tx * 8;

    int ar0 = tid >> 2;                // rows 0..63
    int ar1 = (tid + 256) >> 2;        // rows 64..127
    int ak = (tid & 3) * 4;

    const float* Arow0 = A + (size_t)(i0 + ar0) * Dc + ak;
    const float* Arow1 = A + (size_t)(i0 + ar1) * Dc + ak;
    const float* Brow0 = W + (size_t)(j0 + ar0) * Dc + ak;
    const float* Brow1 = W + (size_t)(j0 + ar1) * Dc + ak;

    float acc[8][8] = {};

    for (int k0 = 0; k0 < Dc; k0 += 16) {
        float4 a0 = *(const float4*)(Arow0 + k0);
        float4 a1 = *(const float4*)(Arow1 + k0);
        float4 b0 = *(const float4*)(Brow0 + k0);
        float4 b1 = *(const float4*)(Brow1 + k0);
        __syncthreads();
        As[ak + 0][ar0] = a0.x; As[ak + 1][ar0] = a0.y; As[ak + 2][ar0] = a0.z; As[ak + 3][ar0] = a0.w;
        As[ak + 0][ar1] = a1.x; As[ak + 1][ar1] = a1.y; As[ak + 2][ar1] = a1.z; As[ak + 3][ar1] = a1.w;
        Bs[ak + 0][ar0] = b0.x; Bs[ak + 1][ar0] = b0.y; Bs[ak + 2][ar0] = b0.z; Bs[ak + 3][ar0] = b0.w;
        Bs[ak + 0][ar1] = b1.x; Bs[ak + 1][ar1] = b1.y; Bs[ak + 2][ar1] = b1.z; Bs[ak + 3][ar1] = b1.w;
        __syncthreads();
        #pragma unroll
        for (int k = 0; k < 16; ++k) {
            float4 av0 = *(const float4*)&As[k][r];
            float4 av1 = *(const float4*)&As[k][r + 4];
            float4 bv0 = *(const float4*)&Bs[k][c];
            float4 bv1 = *(const float4*)&Bs[k][c + 4];
            float a_[8] = {av0.x, av0.y, av0.z, av0.w, av1.x, av1.y, av1.z, av1.w};
            float b_[8] = {bv0.x, bv0.y, bv0.z, bv0.w, bv1.x, bv1.y, bv1.z, bv1.w};
            #pragma unroll
            for (int m = 0; m < 8; ++m)
                #pragma unroll
                for (int n = 0; n < 8; ++n)
                    acc[m][n] = fmaf(a_[m], b_[n], acc[m][n]);
        }
    }

    float4 bb0 = *(const float4*)(bias + j0 + c);
    float4 bb1 = *(const float4*)(bias + j0 + c + 4);
    float bj[8] = {bb0.x, bb0.y, bb0.z, bb0.w, bb1.x, bb1.y, bb1.z, bb1.w};

    #pragma unroll
    for (int m = 0; m < 8; ++m) {
        int row = i0 + r + m;
        float o[8];
        #pragma unroll
        for (int n = 0; n < 8; ++n) o[n] = acc[m][n] + bj[n];
        if (MODE == 1) {
            #pragma unroll
            for (int n = 0; n < 8; ++n) o[n] = gelu_exact(o[n]);
        }
        if (MODE == 2) {
            float gt = gate[row];
            float4 x0 = *(const float4*)(xres + (size_t)row * Dc + j0 + c);
            float4 x1 = *(const float4*)(xres + (size_t)row * Dc + j0 + c + 4);
            float xv[8] = {x0.x, x0.y, x0.z, x0.w, x1.x, x1.y, x1.z, x1.w};
            #pragma unroll
            for (int n = 0; n < 8; ++n) o[n] = xv[n] + gt * o[n];
        }
        float4 s0 = {o[0], o[1], o[2], o[3]};
        float4 s1 = {o[4], o[5], o[6], o[7]};
        *(float4*)(C + (size_t)row * NOUT + j0 + c) = s0;
        *(float4*)(C + (size_t)row * NOUT + j0 + c + 4) = s1;
    }
}

// ---------------------------------------------------------------------------
// K7: attention probs.  grid (B*H, T/256).  K-head tile staged in LDS.
// ---------------------------------------------------------------------------
__global__ __launch_bounds__(256) void probs_kernel(const float* __restrict__ Q,
                                                    const float* __restrict__ Kbuf,
                                                    float* __restrict__ probs) {
    int bh = blockIdx.x;
    int b = bh >> 3, h = bh & 7;
    int t = blockIdx.y * 256 + threadIdx.x;
    __shared__ float Ks[TOPKc][DKc];
    for (int l = threadIdx.x; l < 512; l += 256) {
        int kk = l >> 5, dd = l & 31;
        ((float4*)&Ks[kk][0])[dd] =
            ((const float4*)(Kbuf + (size_t)(b * TOPKc + kk) * Dc + h * DKc))[dd];
    }
    __syncthreads();
    const float* qrow = Q + ((size_t)(b * Tc + t)) * Dc + h * DKc;
    float logit[TOPKc] = {};
    #pragma unroll
    for (int ch = 0; ch < 4; ++ch) {
        float4 qv[8];
        #pragma unroll
        for (int u = 0; u < 8; ++u) qv[u] = ((const float4*)qrow)[ch * 8 + u];
        #pragma unroll
        for (int kk = 0; kk < TOPKc; ++kk) {
            const float4* kr = (const float4*)&Ks[kk][ch * 32];
            float s = 0.f;
            #pragma unroll
            for (int u = 0; u < 8; ++u) s += dot4(qv[u], kr[u]);
            logit[kk] += s;
        }
    }
    constexpr float scale = 0.08838834764831845f;  // 1/sqrt(128)
    float mx = -3e38f;
    #pragma unroll
    for (int kk = 0; kk < TOPKc; ++kk) { logit[kk] *= scale; mx = fmaxf(mx, logit[kk]); }
    float sum = 0.f;
    #pragma unroll
    for (int kk = 0; kk < TOPKc; ++kk) { logit[kk] = expf(logit[kk] - mx); sum += logit[kk]; }
    float inv = 1.0f / sum;
    float* dst = probs + ((size_t)bh * Tc + t) * TOPKc;
    #pragma unroll
    for (int u = 0; u < 4; ++u) {
        float4 p4 = {logit[u * 4] * inv, logit[u * 4 + 1] * inv,
                     logit[u * 4 + 2] * inv, logit[u * 4 + 3] * inv};
        ((float4*)dst)[u] = p4;
    }
}

// ---------------------------------------------------------------------------
// K8: out_att[row][j] = sum_kk p[h(j)][kk] * V[b][kk][j].  Block per row.
// ---------------------------------------------------------------------------
__global__ __launch_bounds__(256) void attout_kernel(const float* __restrict__ probs,
                                                     const float* __restrict__ Vbuf,
                                                     float* __restrict__ attout) {
    int row = blockIdx.x;
    int b = row >> 11;           // T = 2048
    int t = row & (Tc - 1);
    __shared__ float p[Hc * TOPKc];  // 128
    if (threadIdx.x < 32) {
        int h = threadIdx.x >> 2, q = threadIdx.x & 3;
        ((float4*)p)[threadIdx.x] =
            ((const float4*)(probs + ((size_t)(b * Hc + h) * Tc + t) * TOPKc))[q];
    }
    __syncthreads();
    #pragma unroll
    for (int jj = 0; jj < 4; ++jj) {
        int j = jj * 256 + threadIdx.x;
        int h = j >> 7;
        float acc = 0.f;
        #pragma unroll
        for (int kk = 0; kk < TOPKc; ++kk)
            acc += p[h * TOPKc + kk] * Vbuf[(size_t)(b * TOPKc + kk) * Dc + j];
        attout[(size_t)row * Dc + j] = acc;
    }
}

// ---------------------------------------------------------------------------
// K9: gate = sigmoid(g @ g2W^T + g2b).  One wave per row.
// ---------------------------------------------------------------------------
__global__ __launch_bounds__(256) void gate_kernel(const float* __restrict__ g,
                                                   const float* __restrict__ g2W,
                                                   const float* __restrict__ g2b,
                                                   float* __restrict__ gate) {
    int lane = threadIdx.x & 63;
    int row = (blockIdx.x * 256 + threadIdx.x) >> 6;
    float4 w0 = ((const float4*)g2W)[lane];
    float4 w1 = ((const float4*)g2W)[lane + 64];
    const float4* gr = (const float4*)(g + (size_t)row * DMc);
    float4 v0 = gr[lane], v1 = gr[lane + 64];
    float s = dot4(v0, w0) + dot4(v1, w1);
    #pragma unroll
    for (int off = 1; off < 64; off <<= 1) s += __shfl_xor(s, off, 64);
    if (lane == 0) gate[row] = 1.0f / (1.0f + expf(-(s + g2b[0])));
}

// ---------------------------------------------------------------------------
extern "C" void kernel_launch(void* const* d_in, const int* in_sizes, int n_in,
                              void* d_out, int out_size, void* d_ws, size_t ws_size,
                              hipStream_t stream) {
    const float* x    = (const float*)d_in[0];
    const float* memk = (const float*)d_in[1];
    const float* memv = (const float*)d_in[2];
    const float* ln_g = (const float*)d_in[3];
    const float* ln_b = (const float*)d_in[4];
    const float* qW   = (const float*)d_in[5];
    const float* qb   = (const float*)d_in[6];
    const float* kW   = (const float*)d_in[7];
    const float* kb   = (const float*)d_in[8];
    const float* vW   = (const float*)d_in[9];
    const float* vb   = (const float*)d_in[10];
    const float* oW   = (const float*)d_in[11];
    const float* ob   = (const float*)d_in[12];
    const float* g1W  = (const float*)d_in[13];
    const float* g1b  = (const float*)d_in[14];
    const float* g2W  = (const float*)d_in[15];
    const float* g2b  = (const float*)d_in[16];
    int M = in_sizes[1] / DMc;

    float* ws = (float*)d_ws;
    size_t off = 0;
    float* h_in = ws + off;  off += (size_t)Nc * Dc;        // 8388608
    float* Qbuf = ws + off;  off += (size_t)Nc * Dc;        // reused as attout
    float* gbuf = ws + off;  off += (size_t)Nc * DMc;       // 4194304
    float* sim  = ws + off;  off += (size_t)Bc * M;
    float* qsum = ws + off;  off += Bc * DMc;
    float* qn   = ws + off;  off += Bc * DMc;
    float* Kbuf = ws + off;  off += (size_t)Bc * TOPKc * Dc;
    float* Vbuf = ws + off;  off += (size_t)Bc * TOPKc * Dc;
    float* probs= ws + off;  off += (size_t)Bc * Hc * Tc * TOPKc;
    float* gate = ws + off;  off += Nc;
    int*   tidx = (int*)(ws + off);
    float* out  = (float*)d_out;

    hipMemsetAsync(qsum, 0, Bc * DMc * sizeof(float), stream);

    ln_kernel<<<Nc, 256, 0, stream>>>(x, ln_g, ln_b, h_in);
    qsum_kernel<<<dim3(Bc, 64), 256, 0, stream>>>(h_in, qsum);
    qnorm_kernel<<<Bc, 256, 0, stream>>>(qsum, qn);
    sim_kernel<<<1024, 256, 0, stream>>>(memk, qn, sim, M);
    topk_kernel<<<Bc, 256, 0, stream>>>(sim, tidx, M);
    kv_kernel<<<128, 256, 0, stream>>>(memk, memv, tidx, kW, kb, vW, vb, Kbuf, Vbuf);
    gemm_kernel<0, 1024><<<dim3(Nc / 128, 8), 256, 0, stream>>>(h_in, qW, qb, Qbuf,
                                                                nullptr, nullptr);
    probs_kernel<<<dim3(Bc * Hc, Tc / 256), 256, 0, stream>>>(Qbuf, Kbuf, probs);
    gemm_kernel<1, 512><<<dim3(Nc / 128, 4), 256, 0, stream>>>(h_in, g1W, g1b, gbuf,
                                                               nullptr, nullptr);
    // attout overwrites Qbuf (Q dead after probs)
    attout_kernel<<<Nc, 256, 0, stream>>>(probs, Vbuf, Qbuf);
    gate_kernel<<<Nc / 4, 256, 0, stream>>>(gbuf, g2W, g2b, gate);
    gemm_kernel<2, 1024><<<dim3(Nc / 128, 8), 256, 0, stream>>>(Qbuf, oW, ob, out,
                                                                x, gate);
}

// Round 2
// 1118.793 us; speedup vs baseline: 1.2844x; 1.2844x over previous
//
#include <hip/hip_runtime.h>
#include <cstddef>
#include <cstdint>
#include <math.h>

// Problem constants (match reference setup_inputs)
constexpr int Bc = 4;
constexpr int Tc = 2048;
constexpr int Dc = 1024;
constexpr int DMc = 512;
constexpr int Hc = 8;
constexpr int DKc = 128;
constexpr int Nc = Bc * Tc;       // 8192 rows
constexpr int TOPKc = 16;
constexpr int NCH = 128;          // top-k pass-1 chunks per batch row

// ---------------------------------------------------------------------------
// K1: LayerNorm.  One block (256 thr) per row; float4 loads; block reduce.
// ---------------------------------------------------------------------------
__global__ __launch_bounds__(256) void ln_kernel(const float* __restrict__ x,
                                                 const float* __restrict__ g,
                                                 const float* __restrict__ b,
                                                 float* __restrict__ h) {
    int row = blockIdx.x;
    const float4* xr = (const float4*)(x + (size_t)row * Dc);
    float4 v = xr[threadIdx.x];
    float s  = v.x + v.y + v.z + v.w;
    float ss = v.x * v.x + v.y * v.y + v.z * v.z + v.w * v.w;
    #pragma unroll
    for (int off = 1; off < 64; off <<= 1) {
        s  += __shfl_xor(s,  off, 64);
        ss += __shfl_xor(ss, off, 64);
    }
    __shared__ float rs[4], rss[4];
    int wv = threadIdx.x >> 6, ln = threadIdx.x & 63;
    if (ln == 0) { rs[wv] = s; rss[wv] = ss; }
    __syncthreads();
    s  = rs[0] + rs[1] + rs[2] + rs[3];
    ss = rss[0] + rss[1] + rss[2] + rss[3];
    float mu  = s * (1.0f / Dc);
    float var = ss * (1.0f / Dc) - mu * mu;
    float rstd = rsqrtf(var + 1e-5f);
    float4 gg = ((const float4*)g)[threadIdx.x];
    float4 bb = ((const float4*)b)[threadIdx.x];
    float4 o;
    o.x = (v.x - mu) * rstd * gg.x + bb.x;
    o.y = (v.y - mu) * rstd * gg.y + bb.y;
    o.z = (v.z - mu) * rstd * gg.z + bb.z;
    o.w = (v.w - mu) * rstd * gg.w + bb.w;
    ((float4*)(h + (size_t)row * Dc))[threadIdx.x] = o;
}

// ---------------------------------------------------------------------------
// K2a: column-sum of h_in over T (first 512 dims only) -> qsum via atomics.
// grid (B, 64) blocks, each handles 32 rows.
// ---------------------------------------------------------------------------
__global__ __launch_bounds__(256) void qsum_kernel(const float* __restrict__ h,
                                                   float* __restrict__ qsum) {
    int b = blockIdx.x;
    int chunk = blockIdx.y;
    int d0 = threadIdx.x, d1 = threadIdx.x + 256;
    const float* base = h + ((size_t)b * Tc + (size_t)chunk * 32) * Dc;
    float a0 = 0.f, a1 = 0.f;
    #pragma unroll 4
    for (int r = 0; r < 32; ++r) {
        a0 += base[(size_t)r * Dc + d0];
        a1 += base[(size_t)r * Dc + d1];
    }
    atomicAdd(&qsum[b * DMc + d0], a0);
    atomicAdd(&qsum[b * DMc + d1], a1);
}

// K2b: normalize q summary: qn = (qsum/T) / max(||qsum/T||, 1e-12)
__global__ __launch_bounds__(256) void qnorm_kernel(const float* __restrict__ qsum,
                                                    float* __restrict__ qn) {
    int b = blockIdx.x;
    float v0 = qsum[b * DMc + threadIdx.x] * (1.0f / Tc);
    float v1 = qsum[b * DMc + threadIdx.x + 256] * (1.0f / Tc);
    float ss = v0 * v0 + v1 * v1;
    #pragma unroll
    for (int off = 1; off < 64; off <<= 1) ss += __shfl_xor(ss, off, 64);
    __shared__ float red[4];
    int wv = threadIdx.x >> 6, ln = threadIdx.x & 63;
    if (ln == 0) red[wv] = ss;
    __syncthreads();
    ss = red[0] + red[1] + red[2] + red[3];
    float inv = 1.0f / fmaxf(sqrtf(ss), 1e-12f);
    qn[b * DMc + threadIdx.x] = v0 * inv;
    qn[b * DMc + threadIdx.x + 256] = v1 * inv;
}

__device__ inline float dot4(float4 a, float4 b) {
    return a.x * b.x + a.y * b.y + a.z * b.z + a.w * b.w;
}

// ---------------------------------------------------------------------------
// K3: sim[b][r] = dot(qn[b], keys[r]) / max(||keys[r]||, 1e-12)
// One wave per row, grid-stride. 205 MB read -> HBM-bound.
// ---------------------------------------------------------------------------
__global__ __launch_bounds__(256) void sim_kernel(const float* __restrict__ keys,
                                                  const float* __restrict__ qn,
                                                  float* __restrict__ sim, int M) {
    int lane = threadIdx.x & 63;
    int wave = (blockIdx.x * 256 + threadIdx.x) >> 6;
    int nw = (gridDim.x * 256) >> 6;
    const float4* qf = (const float4*)qn;  // 128 float4 per b
    float4 q[4][2];
    #pragma unroll
    for (int b = 0; b < 4; ++b) {
        q[b][0] = qf[b * 128 + lane];
        q[b][1] = qf[b * 128 + 64 + lane];
    }
    for (int r = wave; r < M; r += nw) {
        const float4* kr = (const float4*)(keys + (size_t)r * DMc);
        float4 k0 = kr[lane], k1 = kr[lane + 64];
        float nn = dot4(k0, k0) + dot4(k1, k1);
        float d0 = dot4(k0, q[0][0]) + dot4(k1, q[0][1]);
        float d1 = dot4(k0, q[1][0]) + dot4(k1, q[1][1]);
        float d2 = dot4(k0, q[2][0]) + dot4(k1, q[2][1]);
        float d3 = dot4(k0, q[3][0]) + dot4(k1, q[3][1]);
        #pragma unroll
        for (int off = 1; off < 64; off <<= 1) {
            nn += __shfl_xor(nn, off, 64);
            d0 += __shfl_xor(d0, off, 64);
            d1 += __shfl_xor(d1, off, 64);
            d2 += __shfl_xor(d2, off, 64);
            d3 += __shfl_xor(d3, off, 64);
        }
        if (lane == 0) {
            float inv = 1.0f / fmaxf(sqrtf(nn), 1e-12f);
            sim[(size_t)0 * M + r] = d0 * inv;
            sim[(size_t)1 * M + r] = d1 * inv;
            sim[(size_t)2 * M + r] = d2 * inv;
            sim[(size_t)3 * M + r] = d3 * inv;
        }
    }
}

// ---------------------------------------------------------------------------
// K4: top-16 per b, two-pass parallel selection.
// Keys packed as (monotone_u32(value) << 32) | index so uint64 max == float
// argmax. Only the SET of indices matters downstream (softmax over k is
// permutation-invariant), exact-tie order differences are acceptable.
// ---------------------------------------------------------------------------
__device__ inline uint32_t fkey(float f) {
    uint32_t u = __float_as_uint(f);
    return (u & 0x80000000u) ? ~u : (u | 0x80000000u);
}

__device__ inline unsigned long long block_max_u64(unsigned long long mx,
                                                   unsigned long long* wred) {
    int lane = threadIdx.x & 63, wv = threadIdx.x >> 6;
    #pragma unroll
    for (int off = 1; off < 64; off <<= 1) {
        unsigned long long o = __shfl_xor(mx, off, 64);
        if (o > mx) mx = o;
    }
    if (lane == 0) wred[wv] = mx;
    __syncthreads();
    unsigned long long w = wred[0];
    #pragma unroll
    for (int j = 1; j < 4; ++j) if (wred[j] > w) w = wred[j];
    return w;
}

// Pass 1: grid (B, NCH). Each block: local top-16 of its ~M/NCH chunk.
__global__ __launch_bounds__(256) void topk_pass1(const float* __restrict__ sim,
                                                  unsigned long long* __restrict__ cand,
                                                  int M, int CH) {
    int b = blockIdx.x, chunk = blockIdx.y;
    __shared__ unsigned long long keys[1024];
    __shared__ unsigned long long wred[4];
    for (int i = threadIdx.x; i < CH; i += 256) {
        int gi = chunk * CH + i;
        unsigned long long key = 0ull;
        if (gi < M) {
            float v = sim[(size_t)b * M + gi];
            key = ((unsigned long long)fkey(v) << 32) | (unsigned)gi;
        }
        keys[i] = key;
    }
    __syncthreads();
    for (int sel = 0; sel < TOPKc; ++sel) {
        unsigned long long mx = 0ull;
        for (int i = threadIdx.x; i < CH; i += 256)
            if (keys[i] > mx) mx = keys[i];
        unsigned long long w = block_max_u64(mx, wred);
        if (threadIdx.x == 0)
            cand[((size_t)b * NCH + chunk) * TOPKc + sel] = w;
        for (int i = threadIdx.x; i < CH; i += 256)
            if (keys[i] == w) keys[i] = 0ull;
        __syncthreads();
    }
}

// Pass 2: one block per b; top-16 of NCH*16 = 2048 candidates.
__global__ __launch_bounds__(256) void topk_pass2(const unsigned long long* __restrict__ cand,
                                                  int* __restrict__ top_idx) {
    int b = blockIdx.x;
    constexpr int CH2 = NCH * TOPKc;  // 2048
    __shared__ unsigned long long keys[CH2];
    __shared__ unsigned long long wred[4];
    for (int i = threadIdx.x; i < CH2; i += 256)
        keys[i] = cand[(size_t)b * CH2 + i];
    __syncthreads();
    for (int sel = 0; sel < TOPKc; ++sel) {
        unsigned long long mx = 0ull;
        for (int i = threadIdx.x; i < CH2; i += 256)
            if (keys[i] > mx) mx = keys[i];
        unsigned long long w = block_max_u64(mx, wred);
        if (threadIdx.x == 0)
            top_idx[b * TOPKc + sel] = (int)(w & 0xFFFFFFFFull);
        for (int i = threadIdx.x; i < CH2; i += 256)
            if (keys[i] == w) keys[i] = 0ull;
        __syncthreads();
    }
}

// ---------------------------------------------------------------------------
// K5: gather + K/V projection.  128 blocks: (kv, b, kk).
// ---------------------------------------------------------------------------
__global__ __launch_bounds__(256) void kv_kernel(const float* __restrict__ memk,
                                                 const float* __restrict__ memv,
                                                 const int* __restrict__ top_idx,
                                                 const float* __restrict__ kW,
                                                 const float* __restrict__ kb,
                                                 const float* __restrict__ vW,
                                                 const float* __restrict__ vb,
                                                 float* __restrict__ Kbuf,
                                                 float* __restrict__ Vbuf) {
    int id = blockIdx.x;
    int kv = id >> 6;
    int b = (id >> 4) & 3;
    int kk = id & 15;
    int ridx = top_idx[b * TOPKc + kk];
    const float* src = (kv ? memv : memk) + (size_t)ridx * DMc;
    const float* W = kv ? vW : kW;
    const float* bias = kv ? vb : kb;
    float* dst = (kv ? Vbuf : Kbuf) + (size_t)(b * TOPKc + kk) * Dc;
    __shared__ float srow[DMc];
    if (threadIdx.x < 128) ((float4*)srow)[threadIdx.x] = ((const float4*)src)[threadIdx.x];
    __syncthreads();
    #pragma unroll
    for (int jj = 0; jj < 4; ++jj) {
        int j = threadIdx.x + jj * 256;
        const float4* wr = (const float4*)(W + (size_t)j * DMc);
        float acc = 0.f;
        #pragma unroll 4
        for (int c = 0; c < DMc / 4; ++c) {
            float4 w = wr[c];
            float4 s = ((const float4*)srow)[c];
            acc += w.x * s.x + w.y * s.y + w.z * s.z + w.w * s.w;
        }
        dst[j] = acc + bias[j];
    }
}

// ---------------------------------------------------------------------------
// K6: fp32 tiled GEMM  C(N x NOUT) = A(N x 1024) @ W(NOUT x 1024)^T + bias
// 128x128 tile, BK=16, 256 threads, 8x8 acc/thread.
// MODE 0: plain (Q proj)   MODE 1: gelu (G1)   MODE 2: out = x + gate*(.)
// ---------------------------------------------------------------------------
__device__ inline float gelu_exact(float v) {
    return 0.5f * v * (1.0f + erff(v * 0.70710678118654752f));
}

template <int MODE, int NOUT>
__global__ __launch_bounds__(256) void gemm_kernel(const float* __restrict__ A,
                                                   const float* __restrict__ W,
                                                   const float* __restrict__ bias,
                                                   float* __restrict__ C,
                                                   const float* __restrict__ xres,
                                                   const float* __restrict__ gate) {
    __shared__ float As[16][132];
    __shared__ float Bs[16][132];
    int i0 = blockIdx.x * 128;
    int j0 = blockIdx.y * 128;
    int tid = threadIdx.x;
    int lane = tid & 63, wave = tid >> 6;
    int ty = ((wave >> 1) << 3) + (lane >> 3);   // 0..15
    int tx = ((wave & 1) << 3) + (lane & 7);     // 0..15
    int r = ty * 8, c = tx * 8;

    int ar0 = tid >> 2;                // rows 0..63
    int ar1 = (tid + 256) >> 2;        // rows 64..127
    int ak = (tid & 3) * 4;

    const float* Arow0 = A + (size_t)(i0 + ar0) * Dc + ak;
    const float* Arow1 = A + (size_t)(i0 + ar1) * Dc + ak;
    const float* Brow0 = W + (size_t)(j0 + ar0) * Dc + ak;
    const float* Brow1 = W + (size_t)(j0 + ar1) * Dc + ak;

    float acc[8][8] = {};

    for (int k0 = 0; k0 < Dc; k0 += 16) {
        float4 a0 = *(const float4*)(Arow0 + k0);
        float4 a1 = *(const float4*)(Arow1 + k0);
        float4 b0 = *(const float4*)(Brow0 + k0);
        float4 b1 = *(const float4*)(Brow1 + k0);
        __syncthreads();
        As[ak + 0][ar0] = a0.x; As[ak + 1][ar0] = a0.y; As[ak + 2][ar0] = a0.z; As[ak + 3][ar0] = a0.w;
        As[ak + 0][ar1] = a1.x; As[ak + 1][ar1] = a1.y; As[ak + 2][ar1] = a1.z; As[ak + 3][ar1] = a1.w;
        Bs[ak + 0][ar0] = b0.x; Bs[ak + 1][ar0] = b0.y; Bs[ak + 2][ar0] = b0.z; Bs[ak + 3][ar0] = b0.w;
        Bs[ak + 0][ar1] = b1.x; Bs[ak + 1][ar1] = b1.y; Bs[ak + 2][ar1] = b1.z; Bs[ak + 3][ar1] = b1.w;
        __syncthreads();
        #pragma unroll
        for (int k = 0; k < 16; ++k) {
            float4 av0 = *(const float4*)&As[k][r];
            float4 av1 = *(const float4*)&As[k][r + 4];
            float4 bv0 = *(const float4*)&Bs[k][c];
            float4 bv1 = *(const float4*)&Bs[k][c + 4];
            float a_[8] = {av0.x, av0.y, av0.z, av0.w, av1.x, av1.y, av1.z, av1.w};
            float b_[8] = {bv0.x, bv0.y, bv0.z, bv0.w, bv1.x, bv1.y, bv1.z, bv1.w};
            #pragma unroll
            for (int m = 0; m < 8; ++m)
                #pragma unroll
                for (int n = 0; n < 8; ++n)
                    acc[m][n] = fmaf(a_[m], b_[n], acc[m][n]);
        }
    }

    float4 bb0 = *(const float4*)(bias + j0 + c);
    float4 bb1 = *(const float4*)(bias + j0 + c + 4);
    float bj[8] = {bb0.x, bb0.y, bb0.z, bb0.w, bb1.x, bb1.y, bb1.z, bb1.w};

    #pragma unroll
    for (int m = 0; m < 8; ++m) {
        int row = i0 + r + m;
        float o[8];
        #pragma unroll
        for (int n = 0; n < 8; ++n) o[n] = acc[m][n] + bj[n];
        if (MODE == 1) {
            #pragma unroll
            for (int n = 0; n < 8; ++n) o[n] = gelu_exact(o[n]);
        }
        if (MODE == 2) {
            float gt = gate[row];
            float4 x0 = *(const float4*)(xres + (size_t)row * Dc + j0 + c);
            float4 x1 = *(const float4*)(xres + (size_t)row * Dc + j0 + c + 4);
            float xv[8] = {x0.x, x0.y, x0.z, x0.w, x1.x, x1.y, x1.z, x1.w};
            #pragma unroll
            for (int n = 0; n < 8; ++n) o[n] = xv[n] + gt * o[n];
        }
        float4 s0 = {o[0], o[1], o[2], o[3]};
        float4 s1 = {o[4], o[5], o[6], o[7]};
        *(float4*)(C + (size_t)row * NOUT + j0 + c) = s0;
        *(float4*)(C + (size_t)row * NOUT + j0 + c + 4) = s1;
    }
}

// ---------------------------------------------------------------------------
// K7: attention probs.  grid (B*H, T/256).  K-head tile staged in LDS.
// ---------------------------------------------------------------------------
__global__ __launch_bounds__(256) void probs_kernel(const float* __restrict__ Q,
                                                    const float* __restrict__ Kbuf,
                                                    float* __restrict__ probs) {
    int bh = blockIdx.x;
    int b = bh >> 3, h = bh & 7;
    int t = blockIdx.y * 256 + threadIdx.x;
    __shared__ float Ks[TOPKc][DKc];
    for (int l = threadIdx.x; l < 512; l += 256) {
        int kk = l >> 5, dd = l & 31;
        ((float4*)&Ks[kk][0])[dd] =
            ((const float4*)(Kbuf + (size_t)(b * TOPKc + kk) * Dc + h * DKc))[dd];
    }
    __syncthreads();
    const float* qrow = Q + ((size_t)(b * Tc + t)) * Dc + h * DKc;
    float logit[TOPKc] = {};
    #pragma unroll
    for (int ch = 0; ch < 4; ++ch) {
        float4 qv[8];
        #pragma unroll
        for (int u = 0; u < 8; ++u) qv[u] = ((const float4*)qrow)[ch * 8 + u];
        #pragma unroll
        for (int kk = 0; kk < TOPKc; ++kk) {
            const float4* kr = (const float4*)&Ks[kk][ch * 32];
            float s = 0.f;
            #pragma unroll
            for (int u = 0; u < 8; ++u) s += dot4(qv[u], kr[u]);
            logit[kk] += s;
        }
    }
    constexpr float scale = 0.08838834764831845f;  // 1/sqrt(128)
    float mx = -3e38f;
    #pragma unroll
    for (int kk = 0; kk < TOPKc; ++kk) { logit[kk] *= scale; mx = fmaxf(mx, logit[kk]); }
    float sum = 0.f;
    #pragma unroll
    for (int kk = 0; kk < TOPKc; ++kk) { logit[kk] = expf(logit[kk] - mx); sum += logit[kk]; }
    float inv = 1.0f / sum;
    float* dst = probs + ((size_t)bh * Tc + t) * TOPKc;
    #pragma unroll
    for (int u = 0; u < 4; ++u) {
        float4 p4 = {logit[u * 4] * inv, logit[u * 4 + 1] * inv,
                     logit[u * 4 + 2] * inv, logit[u * 4 + 3] * inv};
        ((float4*)dst)[u] = p4;
    }
}

// ---------------------------------------------------------------------------
// K8: out_att[row][j] = sum_kk p[h(j)][kk] * V[b][kk][j].  Block per row.
// ---------------------------------------------------------------------------
__global__ __launch_bounds__(256) void attout_kernel(const float* __restrict__ probs,
                                                     const float* __restrict__ Vbuf,
                                                     float* __restrict__ attout) {
    int row = blockIdx.x;
    int b = row >> 11;           // T = 2048
    int t = row & (Tc - 1);
    __shared__ float p[Hc * TOPKc];  // 128
    if (threadIdx.x < 32) {
        int h = threadIdx.x >> 2, q = threadIdx.x & 3;
        ((float4*)p)[threadIdx.x] =
            ((const float4*)(probs + ((size_t)(b * Hc + h) * Tc + t) * TOPKc))[q];
    }
    __syncthreads();
    #pragma unroll
    for (int jj = 0; jj < 4; ++jj) {
        int j = jj * 256 + threadIdx.x;
        int h = j >> 7;
        float acc = 0.f;
        #pragma unroll
        for (int kk = 0; kk < TOPKc; ++kk)
            acc += p[h * TOPKc + kk] * Vbuf[(size_t)(b * TOPKc + kk) * Dc + j];
        attout[(size_t)row * Dc + j] = acc;
    }
}

// ---------------------------------------------------------------------------
// K9: gate = sigmoid(g @ g2W^T + g2b).  One wave per row.
// ---------------------------------------------------------------------------
__global__ __launch_bounds__(256) void gate_kernel(const float* __restrict__ g,
                                                   const float* __restrict__ g2W,
                                                   const float* __restrict__ g2b,
                                                   float* __restrict__ gate) {
    int lane = threadIdx.x & 63;
    int row = (blockIdx.x * 256 + threadIdx.x) >> 6;
    float4 w0 = ((const float4*)g2W)[lane];
    float4 w1 = ((const float4*)g2W)[lane + 64];
    const float4* gr = (const float4*)(g + (size_t)row * DMc);
    float4 v0 = gr[lane], v1 = gr[lane + 64];
    float s = dot4(v0, w0) + dot4(v1, w1);
    #pragma unroll
    for (int off = 1; off < 64; off <<= 1) s += __shfl_xor(s, off, 64);
    if (lane == 0) gate[row] = 1.0f / (1.0f + expf(-(s + g2b[0])));
}

// ---------------------------------------------------------------------------
extern "C" void kernel_launch(void* const* d_in, const int* in_sizes, int n_in,
                              void* d_out, int out_size, void* d_ws, size_t ws_size,
                              hipStream_t stream) {
    const float* x    = (const float*)d_in[0];
    const float* memk = (const float*)d_in[1];
    const float* memv = (const float*)d_in[2];
    const float* ln_g = (const float*)d_in[3];
    const float* ln_b = (const float*)d_in[4];
    const float* qW   = (const float*)d_in[5];
    const float* qb   = (const float*)d_in[6];
    const float* kW   = (const float*)d_in[7];
    const float* kb   = (const float*)d_in[8];
    const float* vW   = (const float*)d_in[9];
    const float* vb   = (const float*)d_in[10];
    const float* oW   = (const float*)d_in[11];
    const float* ob   = (const float*)d_in[12];
    const float* g1W  = (const float*)d_in[13];
    const float* g1b  = (const float*)d_in[14];
    const float* g2W  = (const float*)d_in[15];
    const float* g2b  = (const float*)d_in[16];
    int M = in_sizes[1] / DMc;
    int CH = (M + NCH - 1) / NCH;   // 782 for M=100000 (fits keys[1024])

    float* ws = (float*)d_ws;
    size_t off = 0;
    float* h_in = ws + off;  off += (size_t)Nc * Dc;        // 8388608
    float* Qbuf = ws + off;  off += (size_t)Nc * Dc;        // reused as attout
    float* gbuf = ws + off;  off += (size_t)Nc * DMc;       // 4194304
    float* sim  = ws + off;  off += (size_t)Bc * M;
    float* qsum = ws + off;  off += Bc * DMc;
    float* qn   = ws + off;  off += Bc * DMc;
    float* Kbuf = ws + off;  off += (size_t)Bc * TOPKc * Dc;
    float* Vbuf = ws + off;  off += (size_t)Bc * TOPKc * Dc;
    float* probs= ws + off;  off += (size_t)Bc * Hc * Tc * TOPKc;
    float* gate = ws + off;  off += Nc;
    int*   tidx = (int*)(ws + off);  off += 2 * Bc * TOPKc; // (pad to 8B align)
    unsigned long long* cand = (unsigned long long*)(ws + off);
    // cand: B * NCH * 16 u64 = 64 KB
    float* out  = (float*)d_out;

    hipMemsetAsync(qsum, 0, Bc * DMc * sizeof(float), stream);

    ln_kernel<<<Nc, 256, 0, stream>>>(x, ln_g, ln_b, h_in);
    qsum_kernel<<<dim3(Bc, 64), 256, 0, stream>>>(h_in, qsum);
    qnorm_kernel<<<Bc, 256, 0, stream>>>(qsum, qn);
    sim_kernel<<<1024, 256, 0, stream>>>(memk, qn, sim, M);
    topk_pass1<<<dim3(Bc, NCH), 256, 0, stream>>>(sim, cand, M, CH);
    topk_pass2<<<Bc, 256, 0, stream>>>(cand, tidx);
    kv_kernel<<<128, 256, 0, stream>>>(memk, memv, tidx, kW, kb, vW, vb, Kbuf, Vbuf);
    gemm_kernel<0, 1024><<<dim3(Nc / 128, 8), 256, 0, stream>>>(h_in, qW, qb, Qbuf,
                                                                nullptr, nullptr);
    probs_kernel<<<dim3(Bc * Hc, Tc / 256), 256, 0, stream>>>(Qbuf, Kbuf, probs);
    gemm_kernel<1, 512><<<dim3(Nc / 128, 4), 256, 0, stream>>>(h_in, g1W, g1b, gbuf,
                                                               nullptr, nullptr);
    // attout overwrites Qbuf (Q dead after probs)
    attout_kernel<<<Nc, 256, 0, stream>>>(probs, Vbuf, Qbuf);
    gate_kernel<<<Nc / 4, 256, 0, stream>>>(gbuf, g2W, g2b, gate);
    gemm_kernel<2, 1024><<<dim3(Nc / 128, 8), 256, 0, stream>>>(Qbuf, oW, ob, out,
                                                                x, gate);
}

// Round 3
// 709.757 us; speedup vs baseline: 2.0247x; 1.5763x over previous
//
#include <hip/hip_runtime.h>
#include <cstddef>
#include <cstdint>
#include <math.h>

// Problem constants (match reference setup_inputs)
constexpr int Bc = 4;
constexpr int Tc = 2048;
constexpr int Dc = 1024;
constexpr int DMc = 512;
constexpr int Hc = 8;
constexpr int DKc = 128;
constexpr int Nc = Bc * Tc;       // 8192 rows
constexpr int TOPKc = 16;
constexpr int NCH = 128;          // top-k pass-1 chunks per batch row

typedef __attribute__((ext_vector_type(8))) short bfrag;   // 8 bf16 (4 VGPR)
typedef __attribute__((ext_vector_type(4))) float ffrag;   // 4 f32 acc

// fp32 -> bf16 round-to-nearest-even (raw bits; MFMA consumes bit patterns)
__device__ __forceinline__ unsigned short f2bf(float f) {
    unsigned u = __float_as_uint(f);
    u += 0x7fffu + ((u >> 16) & 1u);
    return (unsigned short)(u >> 16);
}

// async global->LDS, 16B per lane (dest must be lane-linear; see rule #21)
__device__ __forceinline__ void gload_lds16(const void* g, void* l) {
    __builtin_amdgcn_global_load_lds(
        (const __attribute__((address_space(1))) char*)g,
        (__attribute__((address_space(3))) char*)l, 16, 0, 0);
}

__device__ inline float dot4(float4 a, float4 b) {
    return a.x * b.x + a.y * b.y + a.z * b.z + a.w * b.w;
}

// ---------------------------------------------------------------------------
// K0: fp32 -> bf16 weight conversion (run every call; ~2 us total)
// ---------------------------------------------------------------------------
__global__ __launch_bounds__(256) void f2bf_kernel(const float* __restrict__ in,
                                                   unsigned short* __restrict__ out) {
    int i = blockIdx.x * 256 + threadIdx.x;
    float4 v = ((const float4*)in)[i];
    ushort4 u = make_ushort4(f2bf(v.x), f2bf(v.y), f2bf(v.z), f2bf(v.w));
    ((ushort4*)out)[i] = u;
}

// ---------------------------------------------------------------------------
// K1: LayerNorm. One block (256 thr) per row. Emits bf16 h (GEMM A-operand)
// and fp32 first-512-cols copy (exact q_summary path -> stable top-k).
// ---------------------------------------------------------------------------
__global__ __launch_bounds__(256) void ln_kernel(const float* __restrict__ x,
                                                 const float* __restrict__ g,
                                                 const float* __restrict__ b,
                                                 unsigned short* __restrict__ hbf,
                                                 float* __restrict__ h32) {
    int row = blockIdx.x;
    const float4* xr = (const float4*)(x + (size_t)row * Dc);
    float4 v = xr[threadIdx.x];
    float s  = v.x + v.y + v.z + v.w;
    float ss = v.x * v.x + v.y * v.y + v.z * v.z + v.w * v.w;
    #pragma unroll
    for (int off = 1; off < 64; off <<= 1) {
        s  += __shfl_xor(s,  off, 64);
        ss += __shfl_xor(ss, off, 64);
    }
    __shared__ float rs[4], rss[4];
    int wv = threadIdx.x >> 6, ln = threadIdx.x & 63;
    if (ln == 0) { rs[wv] = s; rss[wv] = ss; }
    __syncthreads();
    s  = rs[0] + rs[1] + rs[2] + rs[3];
    ss = rss[0] + rss[1] + rss[2] + rss[3];
    float mu  = s * (1.0f / Dc);
    float var = ss * (1.0f / Dc) - mu * mu;
    float rstd = rsqrtf(var + 1e-5f);
    float4 gg = ((const float4*)g)[threadIdx.x];
    float4 bb = ((const float4*)b)[threadIdx.x];
    float4 o;
    o.x = (v.x - mu) * rstd * gg.x + bb.x;
    o.y = (v.y - mu) * rstd * gg.y + bb.y;
    o.z = (v.z - mu) * rstd * gg.z + bb.z;
    o.w = (v.w - mu) * rstd * gg.w + bb.w;
    ushort4 u = make_ushort4(f2bf(o.x), f2bf(o.y), f2bf(o.z), f2bf(o.w));
    ((ushort4*)(hbf + (size_t)row * Dc))[threadIdx.x] = u;
    if (threadIdx.x < 128)
        ((float4*)(h32 + (size_t)row * DMc))[threadIdx.x] = o;
}

// ---------------------------------------------------------------------------
// K2a: column-sum of h32 over T -> qsum via atomics. grid (B, 64).
// ---------------------------------------------------------------------------
__global__ __launch_bounds__(256) void qsum_kernel(const float* __restrict__ h32,
                                                   float* __restrict__ qsum) {
    int b = blockIdx.x;
    int chunk = blockIdx.y;
    int d0 = threadIdx.x, d1 = threadIdx.x + 256;
    const float* base = h32 + ((size_t)b * Tc + (size_t)chunk * 32) * DMc;
    float a0 = 0.f, a1 = 0.f;
    #pragma unroll 4
    for (int r = 0; r < 32; ++r) {
        a0 += base[(size_t)r * DMc + d0];
        a1 += base[(size_t)r * DMc + d1];
    }
    atomicAdd(&qsum[b * DMc + d0], a0);
    atomicAdd(&qsum[b * DMc + d1], a1);
}

// K2b: normalize q summary
__global__ __launch_bounds__(256) void qnorm_kernel(const float* __restrict__ qsum,
                                                    float* __restrict__ qn) {
    int b = blockIdx.x;
    float v0 = qsum[b * DMc + threadIdx.x] * (1.0f / Tc);
    float v1 = qsum[b * DMc + threadIdx.x + 256] * (1.0f / Tc);
    float ss = v0 * v0 + v1 * v1;
    #pragma unroll
    for (int off = 1; off < 64; off <<= 1) ss += __shfl_xor(ss, off, 64);
    __shared__ float red[4];
    int wv = threadIdx.x >> 6, ln = threadIdx.x & 63;
    if (ln == 0) red[wv] = ss;
    __syncthreads();
    ss = red[0] + red[1] + red[2] + red[3];
    float inv = 1.0f / fmaxf(sqrtf(ss), 1e-12f);
    qn[b * DMc + threadIdx.x] = v0 * inv;
    qn[b * DMc + threadIdx.x + 256] = v1 * inv;
}

// ---------------------------------------------------------------------------
// K3: sim[b][r] = dot(qn[b], keys[r]) / max(||keys[r]||, 1e-12). HBM-bound.
// ---------------------------------------------------------------------------
__global__ __launch_bounds__(256) void sim_kernel(const float* __restrict__ keys,
                                                  const float* __restrict__ qn,
                                                  float* __restrict__ sim, int M) {
    int lane = threadIdx.x & 63;
    int wave = (blockIdx.x * 256 + threadIdx.x) >> 6;
    int nw = (gridDim.x * 256) >> 6;
    const float4* qf = (const float4*)qn;
    float4 q[4][2];
    #pragma unroll
    for (int b = 0; b < 4; ++b) {
        q[b][0] = qf[b * 128 + lane];
        q[b][1] = qf[b * 128 + 64 + lane];
    }
    for (int r = wave; r < M; r += nw) {
        const float4* kr = (const float4*)(keys + (size_t)r * DMc);
        float4 k0 = kr[lane], k1 = kr[lane + 64];
        float nn = dot4(k0, k0) + dot4(k1, k1);
        float d0 = dot4(k0, q[0][0]) + dot4(k1, q[0][1]);
        float d1 = dot4(k0, q[1][0]) + dot4(k1, q[1][1]);
        float d2 = dot4(k0, q[2][0]) + dot4(k1, q[2][1]);
        float d3 = dot4(k0, q[3][0]) + dot4(k1, q[3][1]);
        #pragma unroll
        for (int off = 1; off < 64; off <<= 1) {
            nn += __shfl_xor(nn, off, 64);
            d0 += __shfl_xor(d0, off, 64);
            d1 += __shfl_xor(d1, off, 64);
            d2 += __shfl_xor(d2, off, 64);
            d3 += __shfl_xor(d3, off, 64);
        }
        if (lane == 0) {
            float inv = 1.0f / fmaxf(sqrtf(nn), 1e-12f);
            sim[(size_t)0 * M + r] = d0 * inv;
            sim[(size_t)1 * M + r] = d1 * inv;
            sim[(size_t)2 * M + r] = d2 * inv;
            sim[(size_t)3 * M + r] = d3 * inv;
        }
    }
}

// ---------------------------------------------------------------------------
// K4: top-16 per b, two-pass parallel selection via packed u64 max.
// ---------------------------------------------------------------------------
__device__ inline uint32_t fkey(float f) {
    uint32_t u = __float_as_uint(f);
    return (u & 0x80000000u) ? ~u : (u | 0x80000000u);
}

__device__ inline unsigned long long block_max_u64(unsigned long long mx,
                                                   unsigned long long* wred) {
    int lane = threadIdx.x & 63, wv = threadIdx.x >> 6;
    #pragma unroll
    for (int off = 1; off < 64; off <<= 1) {
        unsigned long long o = __shfl_xor(mx, off, 64);
        if (o > mx) mx = o;
    }
    if (lane == 0) wred[wv] = mx;
    __syncthreads();
    unsigned long long w = wred[0];
    #pragma unroll
    for (int j = 1; j < 4; ++j) if (wred[j] > w) w = wred[j];
    return w;
}

__global__ __launch_bounds__(256) void topk_pass1(const float* __restrict__ sim,
                                                  unsigned long long* __restrict__ cand,
                                                  int M, int CH) {
    int b = blockIdx.x, chunk = blockIdx.y;
    __shared__ unsigned long long keys[1024];
    __shared__ unsigned long long wred[4];
    for (int i = threadIdx.x; i < CH; i += 256) {
        int gi = chunk * CH + i;
        unsigned long long key = 0ull;
        if (gi < M) {
            float v = sim[(size_t)b * M + gi];
            key = ((unsigned long long)fkey(v) << 32) | (unsigned)gi;
        }
        keys[i] = key;
    }
    __syncthreads();
    for (int sel = 0; sel < TOPKc; ++sel) {
        unsigned long long mx = 0ull;
        for (int i = threadIdx.x; i < CH; i += 256)
            if (keys[i] > mx) mx = keys[i];
        unsigned long long w = block_max_u64(mx, wred);
        if (threadIdx.x == 0)
            cand[((size_t)b * NCH + chunk) * TOPKc + sel] = w;
        for (int i = threadIdx.x; i < CH; i += 256)
            if (keys[i] == w) keys[i] = 0ull;
        __syncthreads();
    }
}

__global__ __launch_bounds__(256) void topk_pass2(const unsigned long long* __restrict__ cand,
                                                  int* __restrict__ top_idx) {
    int b = blockIdx.x;
    constexpr int CH2 = NCH * TOPKc;  // 2048
    __shared__ unsigned long long keys[CH2];
    __shared__ unsigned long long wred[4];
    for (int i = threadIdx.x; i < CH2; i += 256)
        keys[i] = cand[(size_t)b * CH2 + i];
    __syncthreads();
    for (int sel = 0; sel < TOPKc; ++sel) {
        unsigned long long mx = 0ull;
        for (int i = threadIdx.x; i < CH2; i += 256)
            if (keys[i] > mx) mx = keys[i];
        unsigned long long w = block_max_u64(mx, wred);
        if (threadIdx.x == 0)
            top_idx[b * TOPKc + sel] = (int)(w & 0xFFFFFFFFull);
        for (int i = threadIdx.x; i < CH2; i += 256)
            if (keys[i] == w) keys[i] = 0ull;
        __syncthreads();
    }
}

// ---------------------------------------------------------------------------
// K5: gather + K/V projection (fp32; tiny). 128 blocks: (kv, b, kk).
// ---------------------------------------------------------------------------
__global__ __launch_bounds__(256) void kv_kernel(const float* __restrict__ memk,
                                                 const float* __restrict__ memv,
                                                 const int* __restrict__ top_idx,
                                                 const float* __restrict__ kW,
                                                 const float* __restrict__ kb,
                                                 const float* __restrict__ vW,
                                                 const float* __restrict__ vb,
                                                 float* __restrict__ Kbuf,
                                                 float* __restrict__ Vbuf) {
    int id = blockIdx.x;
    int kv = id >> 6;
    int b = (id >> 4) & 3;
    int kk = id & 15;
    int ridx = top_idx[b * TOPKc + kk];
    const float* src = (kv ? memv : memk) + (size_t)ridx * DMc;
    const float* W = kv ? vW : kW;
    const float* bias = kv ? vb : kb;
    float* dst = (kv ? Vbuf : Kbuf) + (size_t)(b * TOPKc + kk) * Dc;
    __shared__ float srow[DMc];
    if (threadIdx.x < 128) ((float4*)srow)[threadIdx.x] = ((const float4*)src)[threadIdx.x];
    __syncthreads();
    #pragma unroll
    for (int jj = 0; jj < 4; ++jj) {
        int j = threadIdx.x + jj * 256;
        const float4* wr = (const float4*)(W + (size_t)j * DMc);
        float acc = 0.f;
        #pragma unroll 4
        for (int c = 0; c < DMc / 4; ++c) {
            float4 w = wr[c];
            float4 s = ((const float4*)srow)[c];
            acc += w.x * s.x + w.y * s.y + w.z * s.z + w.w * s.w;
        }
        dst[j] = acc + bias[j];
    }
}

// ---------------------------------------------------------------------------
// K6: bf16 MFMA GEMM  C(8192 x NOUT) = A(8192x1024 bf16) @ W(NOUT x 1024)^T
// Tile 128 x BN, BK=64, 256 thr (2x2 waves), mfma_f32_16x16x32_bf16.
// LDS XOR-swizzle: linear dest (global_load_lds) + inverse-swizzled global
// source + swizzled ds_read (rule #21). Frag maps per m89/m91 (guide §3).
// MODE 0: plain   MODE 1: gelu   MODE 2: out = x + gate*(.)
// ---------------------------------------------------------------------------
__device__ inline float gelu_exact(float v) {
    return 0.5f * v * (1.0f + erff(v * 0.70710678118654752f));
}

template <int MODE, int NOUT, int BN>
__global__ __launch_bounds__(256) void gemm_bf(const unsigned short* __restrict__ A,
                                               const unsigned short* __restrict__ W,
                                               const float* __restrict__ bias,
                                               float* __restrict__ C,
                                               const float* __restrict__ xres,
                                               const float* __restrict__ gate) {
    constexpr int FN = BN / 32;      // frag cols per wave
    __shared__ __align__(16) short Atile[128 * 64];
    __shared__ __align__(16) short Btile[BN * 64];
    const int tid = threadIdx.x;
    const int lane = tid & 63;
    const int wave = tid >> 6;
    const int wr = wave >> 1, wc = wave & 1;
    const int i0 = blockIdx.x * 128;
    const int j0 = blockIdx.y * BN;

    ffrag acc[4][FN];
    #pragma unroll
    for (int m = 0; m < 4; ++m)
        #pragma unroll
        for (int n = 0; n < FN; ++n) acc[m][n] = (ffrag){0.f, 0.f, 0.f, 0.f};

    const int srow = tid >> 3;       // 0..31
    const int schunk = tid & 7;      // 16B chunk within 128B row

    for (int t = 0; t < Dc / 64; ++t) {
        const int k0 = t * 64;
        __syncthreads();             // prior compute done; tiles free
        #pragma unroll
        for (int i = 0; i < 4; ++i) {
            int row = i * 32 + srow;
            int cs = schunk ^ (row & 7);             // pre-swizzled source
            gload_lds16(A + (size_t)(i0 + row) * Dc + k0 + cs * 8,
                        &Atile[i * 2048 + tid * 8]);  // lane-linear dest
        }
        #pragma unroll
        for (int i = 0; i < BN / 32; ++i) {
            int row = i * 32 + srow;
            int cs = schunk ^ (row & 7);
            gload_lds16(W + (size_t)(j0 + row) * Dc + k0 + cs * 8,
                        &Btile[i * 2048 + tid * 8]);
        }
        __syncthreads();             // implicit vmcnt(0) drains gload_lds
        #pragma unroll
        for (int kk = 0; kk < 2; ++kk) {
            bfrag af[4], bfv[FN];
            #pragma unroll
            for (int m = 0; m < 4; ++m) {
                int row = wr * 64 + m * 16 + (lane & 15);
                int ch = (kk * 4 + (lane >> 4)) ^ (row & 7);  // swizzled read
                af[m] = *(const bfrag*)&Atile[row * 64 + ch * 8];
            }
            #pragma unroll
            for (int n = 0; n < FN; ++n) {
                int row = wc * (BN / 2) + n * 16 + (lane & 15);
                int ch = (kk * 4 + (lane >> 4)) ^ (row & 7);
                bfv[n] = *(const bfrag*)&Btile[row * 64 + ch * 8];
            }
            #pragma unroll
            for (int m = 0; m < 4; ++m)
                #pragma unroll
                for (int n = 0; n < FN; ++n)
                    acc[m][n] = __builtin_amdgcn_mfma_f32_16x16x32_bf16(
                        af[m], bfv[n], acc[m][n], 0, 0, 0);
        }
    }

    // epilogue: D frag = col (lane&15), rows (lane>>4)*4 + j
    const int cl = lane & 15;
    const int rg = (lane >> 4) * 4;
    #pragma unroll
    for (int n = 0; n < FN; ++n) {
        int col = j0 + wc * (BN / 2) + n * 16 + cl;
        float bv = bias[col];
        #pragma unroll
        for (int m = 0; m < 4; ++m) {
            int row0 = i0 + wr * 64 + m * 16 + rg;
            #pragma unroll
            for (int j = 0; j < 4; ++j) {
                int row = row0 + j;
                float v = acc[m][n][j] + bv;
                if (MODE == 1) v = gelu_exact(v);
                if (MODE == 2) v = xres[(size_t)row * Dc + col] + gate[row] * v;
                C[(size_t)row * NOUT + col] = v;
            }
        }
    }
}

// ---------------------------------------------------------------------------
// K7: attention probs (fp32 Q). grid (B*H, T/256).
// ---------------------------------------------------------------------------
__global__ __launch_bounds__(256) void probs_kernel(const float* __restrict__ Q,
                                                    const float* __restrict__ Kbuf,
                                                    float* __restrict__ probs) {
    int bh = blockIdx.x;
    int b = bh >> 3, h = bh & 7;
    int t = blockIdx.y * 256 + threadIdx.x;
    __shared__ float Ks[TOPKc][DKc];
    for (int l = threadIdx.x; l < 512; l += 256) {
        int kk = l >> 5, dd = l & 31;
        ((float4*)&Ks[kk][0])[dd] =
            ((const float4*)(Kbuf + (size_t)(b * TOPKc + kk) * Dc + h * DKc))[dd];
    }
    __syncthreads();
    const float* qrow = Q + ((size_t)(b * Tc + t)) * Dc + h * DKc;
    float logit[TOPKc] = {};
    #pragma unroll
    for (int ch = 0; ch < 4; ++ch) {
        float4 qv[8];
        #pragma unroll
        for (int u = 0; u < 8; ++u) qv[u] = ((const float4*)qrow)[ch * 8 + u];
        #pragma unroll
        for (int kk = 0; kk < TOPKc; ++kk) {
            const float4* kr = (const float4*)&Ks[kk][ch * 32];
            float s = 0.f;
            #pragma unroll
            for (int u = 0; u < 8; ++u) s += dot4(qv[u], kr[u]);
            logit[kk] += s;
        }
    }
    constexpr float scale = 0.08838834764831845f;  // 1/sqrt(128)
    float mx = -3e38f;
    #pragma unroll
    for (int kk = 0; kk < TOPKc; ++kk) { logit[kk] *= scale; mx = fmaxf(mx, logit[kk]); }
    float sum = 0.f;
    #pragma unroll
    for (int kk = 0; kk < TOPKc; ++kk) { logit[kk] = expf(logit[kk] - mx); sum += logit[kk]; }
    float inv = 1.0f / sum;
    float* dst = probs + ((size_t)bh * Tc + t) * TOPKc;
    #pragma unroll
    for (int u = 0; u < 4; ++u) {
        float4 p4 = {logit[u * 4] * inv, logit[u * 4 + 1] * inv,
                     logit[u * 4 + 2] * inv, logit[u * 4 + 3] * inv};
        ((float4*)dst)[u] = p4;
    }
}

// ---------------------------------------------------------------------------
// K8: attout (bf16 out -> O-GEMM A operand). Block per row, 4 cols/thread.
// ---------------------------------------------------------------------------
__global__ __launch_bounds__(256) void attout_kernel(const float* __restrict__ probs,
                                                     const float* __restrict__ Vbuf,
                                                     unsigned short* __restrict__ attout) {
    int row = blockIdx.x;
    int b = row >> 11;           // T = 2048
    int t = row & (Tc - 1);
    __shared__ float p[Hc * TOPKc];  // 128
    if (threadIdx.x < 32) {
        int h = threadIdx.x >> 2, q = threadIdx.x & 3;
        ((float4*)p)[threadIdx.x] =
            ((const float4*)(probs + ((size_t)(b * Hc + h) * Tc + t) * TOPKc))[q];
    }
    __syncthreads();
    int j = threadIdx.x * 4;     // 4 consecutive cols, same head (128 | 4)
    int h = j >> 7;
    float4 acc = {0.f, 0.f, 0.f, 0.f};
    #pragma unroll
    for (int kk = 0; kk < TOPKc; ++kk) {
        float pv = p[h * TOPKc + kk];
        float4 v = *(const float4*)&Vbuf[(size_t)(b * TOPKc + kk) * Dc + j];
        acc.x += pv * v.x; acc.y += pv * v.y; acc.z += pv * v.z; acc.w += pv * v.w;
    }
    ushort4 o = make_ushort4(f2bf(acc.x), f2bf(acc.y), f2bf(acc.z), f2bf(acc.w));
    *(ushort4*)&attout[(size_t)row * Dc + j] = o;
}

// ---------------------------------------------------------------------------
// K9: gate = sigmoid(g @ g2W^T + g2b). One wave per row (fp32).
// ---------------------------------------------------------------------------
__global__ __launch_bounds__(256) void gate_kernel(const float* __restrict__ g,
                                                   const float* __restrict__ g2W,
                                                   const float* __restrict__ g2b,
                                                   float* __restrict__ gate) {
    int lane = threadIdx.x & 63;
    int row = (blockIdx.x * 256 + threadIdx.x) >> 6;
    float4 w0 = ((const float4*)g2W)[lane];
    float4 w1 = ((const float4*)g2W)[lane + 64];
    const float4* gr = (const float4*)(g + (size_t)row * DMc);
    float4 v0 = gr[lane], v1 = gr[lane + 64];
    float s = dot4(v0, w0) + dot4(v1, w1);
    #pragma unroll
    for (int off = 1; off < 64; off <<= 1) s += __shfl_xor(s, off, 64);
    if (lane == 0) gate[row] = 1.0f / (1.0f + expf(-(s + g2b[0])));
}

// ---------------------------------------------------------------------------
extern "C" void kernel_launch(void* const* d_in, const int* in_sizes, int n_in,
                              void* d_out, int out_size, void* d_ws, size_t ws_size,
                              hipStream_t stream) {
    const float* x    = (const float*)d_in[0];
    const float* memk = (const float*)d_in[1];
    const float* memv = (const float*)d_in[2];
    const float* ln_g = (const float*)d_in[3];
    const float* ln_b = (const float*)d_in[4];
    const float* qW   = (const float*)d_in[5];
    const float* qb   = (const float*)d_in[6];
    const float* kW   = (const float*)d_in[7];
    const float* kb   = (const float*)d_in[8];
    const float* vW   = (const float*)d_in[9];
    const float* vb   = (const float*)d_in[10];
    const float* oW   = (const float*)d_in[11];
    const float* ob   = (const float*)d_in[12];
    const float* g1W  = (const float*)d_in[13];
    const float* g1b  = (const float*)d_in[14];
    const float* g2W  = (const float*)d_in[15];
    const float* g2b  = (const float*)d_in[16];
    int M = in_sizes[1] / DMc;
    int CH = (M + NCH - 1) / NCH;   // 782 for M=100000 (fits keys[1024])

    float* ws = (float*)d_ws;
    size_t off = 0;
    float* h32  = ws + off;  off += (size_t)Nc * DMc;       // 4,194,304
    unsigned short* hbf = (unsigned short*)(ws + off); off += (size_t)Nc * Dc / 2;
    float* Qbuf = ws + off;  off += (size_t)Nc * Dc;        // reused as attout_bf
    float* gbuf = ws + off;  off += (size_t)Nc * DMc;
    float* sim  = ws + off;  off += (size_t)Bc * M;
    float* qsum = ws + off;  off += Bc * DMc;
    float* qn   = ws + off;  off += Bc * DMc;
    float* Kbuf = ws + off;  off += (size_t)Bc * TOPKc * Dc;
    float* Vbuf = ws + off;  off += (size_t)Bc * TOPKc * Dc;
    float* probs= ws + off;  off += (size_t)Bc * Hc * Tc * TOPKc;
    float* gate = ws + off;  off += Nc;
    int*   tidx = (int*)(ws + off);  off += 2 * Bc * TOPKc;
    unsigned long long* cand = (unsigned long long*)(ws + off);
    off += 2 * (size_t)Bc * NCH * TOPKc;                    // u64 = 2 floats
    unsigned short* qWb  = (unsigned short*)(ws + off); off += (size_t)Dc * Dc / 2;
    unsigned short* oWb  = (unsigned short*)(ws + off); off += (size_t)Dc * Dc / 2;
    unsigned short* g1Wb = (unsigned short*)(ws + off); off += (size_t)DMc * Dc / 2;
    unsigned short* attb = (unsigned short*)Qbuf;           // alias (Q dead after probs)
    float* out  = (float*)d_out;

    hipMemsetAsync(qsum, 0, Bc * DMc * sizeof(float), stream);

    f2bf_kernel<<<Dc * Dc / 1024, 256, 0, stream>>>(qW, qWb);
    f2bf_kernel<<<Dc * Dc / 1024, 256, 0, stream>>>(oW, oWb);
    f2bf_kernel<<<DMc * Dc / 1024, 256, 0, stream>>>(g1W, g1Wb);

    ln_kernel<<<Nc, 256, 0, stream>>>(x, ln_g, ln_b, hbf, h32);
    qsum_kernel<<<dim3(Bc, 64), 256, 0, stream>>>(h32, qsum);
    qnorm_kernel<<<Bc, 256, 0, stream>>>(qsum, qn);
    sim_kernel<<<1024, 256, 0, stream>>>(memk, qn, sim, M);
    topk_pass1<<<dim3(Bc, NCH), 256, 0, stream>>>(sim, cand, M, CH);
    topk_pass2<<<Bc, 256, 0, stream>>>(cand, tidx);
    kv_kernel<<<128, 256, 0, stream>>>(memk, memv, tidx, kW, kb, vW, vb, Kbuf, Vbuf);
    gemm_bf<0, 1024, 128><<<dim3(Nc / 128, 8), 256, 0, stream>>>(
        hbf, qWb, qb, Qbuf, nullptr, nullptr);
    probs_kernel<<<dim3(Bc * Hc, Tc / 256), 256, 0, stream>>>(Qbuf, Kbuf, probs);
    gemm_bf<1, 512, 64><<<dim3(Nc / 128, 8), 256, 0, stream>>>(
        hbf, g1Wb, g1b, gbuf, nullptr, nullptr);
    attout_kernel<<<Nc, 256, 0, stream>>>(probs, Vbuf, attb);
    gate_kernel<<<Nc / 4, 256, 0, stream>>>(gbuf, g2W, g2b, gate);
    gemm_bf<2, 1024, 128><<<dim3(Nc / 128, 8), 256, 0, stream>>>(
        attb, oWb, ob, out, x, gate);
}